// Round 1
// baseline (137311.365 us; speedup 1.0000x reference)
//
#include <hip/hip_runtime.h>
#include <math.h>

#define EPSV 1e-5f

struct __align__(16) WS {
  float W1[128]; float b1[32]; float W2[128]; float b2[4];
  float G1[128]; float gb1[32]; float l1g[32]; float l1b[32];
  float G2[1024]; float gb2[32]; float l2g[32]; float l2b[32];
  float G3[128]; float gb3[4];
};

__device__ __forceinline__ float ftanh(float x) {
  // tanh(x) = 1 - 2/(exp(2x)+1); clamp to avoid inf
  x = fminf(15.0f, fmaxf(-15.0f, x));
  float e = __expf(x + x);
  float r = __builtin_amdgcn_rcpf(e + 1.0f);
  return fmaf(-2.0f, r, 1.0f);
}

__device__ __forceinline__ float4 f4ma(float s, float4 w, float4 a) {
  a.x = fmaf(s, w.x, a.x); a.y = fmaf(s, w.y, a.y);
  a.z = fmaf(s, w.z, a.z); a.w = fmaf(s, w.w, a.w);
  return a;
}

__device__ __forceinline__ void lnorm32(float* t, const float* g, const float* b) {
  float s = 0.f, ss = 0.f;
  #pragma unroll
  for (int i = 0; i < 32; ++i) { s += t[i]; ss = fmaf(t[i], t[i], ss); }
  float m = s * 0.03125f;
  float v = fmaf(-m, m, ss * 0.03125f);
  float r = __frsqrt_rn(v + EPSV);
  #pragma unroll
  for (int i = 0; i < 32; ++i) t[i] = fmaf((t[i] - m) * r, g[i], b[i]);
}

__device__ __forceinline__ void fode(const WS* w, const float y[4], float out[4]) {
  const float4* W1v  = (const float4*)w->W1;
  const float4* b1v  = (const float4*)w->b1;
  const float4* W2v  = (const float4*)w->W2;
  const float4* G1v  = (const float4*)w->G1;
  const float4* gb1v = (const float4*)w->gb1;
  const float4* G2v  = (const float4*)w->G2;
  const float4* gb2v = (const float4*)w->gb2;
  const float4* G3v  = (const float4*)w->G3;

  // magnitude hidden: tanh(y@W1 + b1)
  float hb[32];
  #pragma unroll
  for (int j = 0; j < 8; ++j) {
    float4 a = b1v[j];
    #pragma unroll
    for (int i = 0; i < 4; ++i) a = f4ma(y[i], W1v[i * 8 + j], a);
    hb[4*j+0] = ftanh(a.x); hb[4*j+1] = ftanh(a.y);
    hb[4*j+2] = ftanh(a.z); hb[4*j+3] = ftanh(a.w);
  }
  // mag = hb @ W2 + b2
  float4 mag = *(const float4*)w->b2;
  #pragma unroll
  for (int i = 0; i < 32; ++i) mag = f4ma(hb[i], W2v[i], mag);

  // gating layer 1: t1 = LN(tanh(y@G1 + gb1))
  float t1[32];
  #pragma unroll
  for (int j = 0; j < 8; ++j) {
    float4 a = gb1v[j];
    #pragma unroll
    for (int i = 0; i < 4; ++i) a = f4ma(y[i], G1v[i * 8 + j], a);
    t1[4*j+0] = ftanh(a.x); t1[4*j+1] = ftanh(a.y);
    t1[4*j+2] = ftanh(a.z); t1[4*j+3] = ftanh(a.w);
  }
  lnorm32(t1, w->l1g, w->l1b);

  // gating layer 2: t2 = LN(tanh(t1@G2 + gb2))
  float t2[32];
  #pragma unroll
  for (int j = 0; j < 8; ++j) {
    float4 a = gb2v[j];
    #pragma unroll
    for (int i = 0; i < 32; ++i) a = f4ma(t1[i], G2v[i * 8 + j], a);
    t2[4*j+0] = ftanh(a.x); t2[4*j+1] = ftanh(a.y);
    t2[4*j+2] = ftanh(a.z); t2[4*j+3] = ftanh(a.w);
  }
  lnorm32(t2, w->l2g, w->l2b);

  // z = t2@G3 + gb3 ; out = mag * exp(-z^2)
  float4 z = *(const float4*)w->gb3;
  #pragma unroll
  for (int i = 0; i < 32; ++i) z = f4ma(t2[i], G3v[i], z);
  out[0] = mag.x * __expf(-z.x * z.x);
  out[1] = mag.y * __expf(-z.y * z.y);
  out[2] = mag.z * __expf(-z.z * z.z);
  out[3] = mag.w * __expf(-z.w * z.w);
}

__global__ __launch_bounds__(256) void ode_kernel(
    const float* __restrict__ s_grid, const float* __restrict__ y0,
    const float* __restrict__ W1, const float* __restrict__ b1,
    const float* __restrict__ W2, const float* __restrict__ b2,
    const float* __restrict__ G1, const float* __restrict__ gb1,
    const float* __restrict__ l1g, const float* __restrict__ l1b,
    const float* __restrict__ G2, const float* __restrict__ gb2,
    const float* __restrict__ l2g, const float* __restrict__ l2b,
    const float* __restrict__ G3, const float* __restrict__ gb3,
    float* __restrict__ out, int T, int B) {
  __shared__ WS w;
  __shared__ float sg[512];
  const int tx = threadIdx.x;

  for (int i = tx; i < 128; i += 256) {
    w.W1[i] = W1[i]; w.W2[i] = W2[i]; w.G1[i] = G1[i]; w.G3[i] = G3[i];
  }
  for (int i = tx; i < 1024; i += 256) w.G2[i] = G2[i];
  if (tx < 32) {
    w.b1[tx] = b1[tx]; w.gb1[tx] = gb1[tx];
    w.l1g[tx] = l1g[tx]; w.l1b[tx] = l1b[tx];
    w.gb2[tx] = gb2[tx];
    w.l2g[tx] = l2g[tx]; w.l2b[tx] = l2b[tx];
  }
  if (tx < 4) { w.b2[tx] = b2[tx]; w.gb3[tx] = gb3[tx]; }
  for (int i = tx; i < T && i < 512; i += 256) sg[i] = s_grid[i];
  __syncthreads();

  const int gid = blockIdx.x * 256 + tx;
  if (gid >= B) return;

  float4 y0v = ((const float4*)y0)[gid];
  float y[4] = {y0v.x, y0v.y, y0v.z, y0v.w};
  ((float4*)out)[gid] = y0v;  // t = 0 row

  for (int t = 0; t < T - 1; ++t) {
    const float h = sg[t + 1] - sg[t];
    float k1[4], k2[4], k3[4], k4[4], yt[4];

    fode(&w, y, k1);
    #pragma unroll
    for (int c = 0; c < 4; ++c) yt[c] = fmaf(0.5f * h, k1[c], y[c]);
    fode(&w, yt, k2);
    #pragma unroll
    for (int c = 0; c < 4; ++c) yt[c] = fmaf(0.5f * h, k2[c], y[c]);
    fode(&w, yt, k3);
    #pragma unroll
    for (int c = 0; c < 4; ++c) yt[c] = fmaf(h, k3[c], y[c]);
    fode(&w, yt, k4);
    #pragma unroll
    for (int c = 0; c < 4; ++c)
      y[c] = fmaf(h * (1.0f / 6.0f), k1[c] + 2.0f * (k2[c] + k3[c]) + k4[c], y[c]);

    float4 yo; yo.x = y[0]; yo.y = y[1]; yo.z = y[2]; yo.w = y[3];
    ((float4*)out)[(size_t)(t + 1) * B + gid] = yo;
  }
}

extern "C" void kernel_launch(void* const* d_in, const int* in_sizes, int n_in,
                              void* d_out, int out_size, void* d_ws, size_t ws_size,
                              hipStream_t stream) {
  const float* s_grid = (const float*)d_in[0];
  const float* y0     = (const float*)d_in[1];
  const float* W1     = (const float*)d_in[2];
  const float* b1     = (const float*)d_in[3];
  const float* W2     = (const float*)d_in[4];
  const float* b2     = (const float*)d_in[5];
  const float* G1     = (const float*)d_in[6];
  const float* gb1    = (const float*)d_in[7];
  const float* l1g    = (const float*)d_in[8];
  const float* l1b    = (const float*)d_in[9];
  const float* G2     = (const float*)d_in[10];
  const float* gb2    = (const float*)d_in[11];
  const float* l2g    = (const float*)d_in[12];
  const float* l2b    = (const float*)d_in[13];
  const float* G3     = (const float*)d_in[14];
  const float* gb3    = (const float*)d_in[15];

  const int T = in_sizes[0];
  const int B = in_sizes[1] / 4;

  dim3 block(256);
  dim3 grid((B + 255) / 256);
  hipLaunchKernelGGL(ode_kernel, grid, block, 0, stream,
                     s_grid, y0, W1, b1, W2, b2, G1, gb1, l1g, l1b,
                     G2, gb2, l2g, l2b, G3, gb3, (float*)d_out, T, B);
}

// Round 2
// 136972.144 us; speedup vs baseline: 1.0025x; 1.0025x over previous
//
#include <hip/hip_runtime.h>
#include <math.h>

#define EPSV 1e-5f

struct __align__(16) WS {
  float W1[128]; float b1[32]; float W2[128]; float b2[4];
  float G1[128]; float gb1[32]; float l1g[32]; float l1b[32];
  float G2[1024]; float gb2[32]; float l2g[32]; float l2b[32];
  float G3[128]; float gb3[4];
};

__device__ __forceinline__ float ftanh(float x) {
  // tanh(x) = 1 - 2/(exp(2x)+1); clamp to avoid inf
  x = fminf(15.0f, fmaxf(-15.0f, x));
  float e = __expf(x + x);
  float r = __builtin_amdgcn_rcpf(e + 1.0f);
  return fmaf(-2.0f, r, 1.0f);
}

__device__ __forceinline__ float4 f4ma(float s, float4 w, float4 a) {
  a.x = fmaf(s, w.x, a.x); a.y = fmaf(s, w.y, a.y);
  a.z = fmaf(s, w.z, a.z); a.w = fmaf(s, w.w, a.w);
  return a;
}

__device__ __forceinline__ void lnorm32(float* t, const float* g, const float* b) {
  float s = 0.f, ss = 0.f;
  #pragma unroll
  for (int i = 0; i < 32; ++i) { s += t[i]; ss = fmaf(t[i], t[i], ss); }
  float m = s * 0.03125f;
  float v = fmaf(-m, m, ss * 0.03125f);
  float r = __frsqrt_rn(v + EPSV);
  #pragma unroll
  for (int i = 0; i < 32; ++i) t[i] = fmaf((t[i] - m) * r, g[i], b[i]);
}

// Register-lean f: peak live state is one 32-float array + 8 float4 accums.
__device__ __forceinline__ void fode(const WS* w, const float y[4], float out[4]) {
  const float4* W1v  = (const float4*)w->W1;
  const float4* b1v  = (const float4*)w->b1;
  const float4* W2v  = (const float4*)w->W2;
  const float4* G1v  = (const float4*)w->G1;
  const float4* gb1v = (const float4*)w->gb1;
  const float4* G2v  = (const float4*)w->G2;
  const float4* gb2v = (const float4*)w->gb2;
  const float4* G3v  = (const float4*)w->G3;

  // magnitude net, fused: no hidden array kept live
  float4 mag = *(const float4*)w->b2;
  #pragma unroll
  for (int j = 0; j < 8; ++j) {
    float4 a = b1v[j];
    #pragma unroll
    for (int i = 0; i < 4; ++i) a = f4ma(y[i], W1v[i * 8 + j], a);
    mag = f4ma(ftanh(a.x), W2v[4 * j + 0], mag);
    mag = f4ma(ftanh(a.y), W2v[4 * j + 1], mag);
    mag = f4ma(ftanh(a.z), W2v[4 * j + 2], mag);
    mag = f4ma(ftanh(a.w), W2v[4 * j + 3], mag);
  }

  // gating layer 1: t = LN(tanh(y@G1 + gb1))
  float t[32];
  #pragma unroll
  for (int j = 0; j < 8; ++j) {
    float4 a = gb1v[j];
    #pragma unroll
    for (int i = 0; i < 4; ++i) a = f4ma(y[i], G1v[i * 8 + j], a);
    t[4*j+0] = ftanh(a.x); t[4*j+1] = ftanh(a.y);
    t[4*j+2] = ftanh(a.z); t[4*j+3] = ftanh(a.w);
  }
  lnorm32(t, w->l1g, w->l1b);

  // gating layer 2: u = LN(tanh(t@G2 + gb2)); t dies as u completes
  float u[32];
  #pragma unroll
  for (int j = 0; j < 8; ++j) {
    float4 a = gb2v[j];
    #pragma unroll
    for (int i = 0; i < 32; ++i) a = f4ma(t[i], G2v[i * 8 + j], a);
    u[4*j+0] = ftanh(a.x); u[4*j+1] = ftanh(a.y);
    u[4*j+2] = ftanh(a.z); u[4*j+3] = ftanh(a.w);
  }
  lnorm32(u, w->l2g, w->l2b);

  // z = u@G3 + gb3 ; out = mag * exp(-z^2)
  float4 z = *(const float4*)w->gb3;
  #pragma unroll
  for (int i = 0; i < 32; ++i) z = f4ma(u[i], G3v[i], z);
  out[0] = mag.x * __expf(-z.x * z.x);
  out[1] = mag.y * __expf(-z.y * z.y);
  out[2] = mag.z * __expf(-z.z * z.z);
  out[3] = mag.w * __expf(-z.w * z.w);
}

__global__ __launch_bounds__(256) void ode_kernel(
    const float* __restrict__ s_grid, const float* __restrict__ y0,
    const float* __restrict__ W1, const float* __restrict__ b1,
    const float* __restrict__ W2, const float* __restrict__ b2,
    const float* __restrict__ G1, const float* __restrict__ gb1,
    const float* __restrict__ l1g, const float* __restrict__ l1b,
    const float* __restrict__ G2, const float* __restrict__ gb2,
    const float* __restrict__ l2g, const float* __restrict__ l2b,
    const float* __restrict__ G3, const float* __restrict__ gb3,
    float* __restrict__ out, int T, int B) {
  __shared__ WS w;
  __shared__ float sg[512];
  const int tx = threadIdx.x;

  for (int i = tx; i < 128; i += 256) {
    w.W1[i] = W1[i]; w.W2[i] = W2[i]; w.G1[i] = G1[i]; w.G3[i] = G3[i];
  }
  for (int i = tx; i < 1024; i += 256) w.G2[i] = G2[i];
  if (tx < 32) {
    w.b1[tx] = b1[tx]; w.gb1[tx] = gb1[tx];
    w.l1g[tx] = l1g[tx]; w.l1b[tx] = l1b[tx];
    w.gb2[tx] = gb2[tx];
    w.l2g[tx] = l2g[tx]; w.l2b[tx] = l2b[tx];
  }
  if (tx < 4) { w.b2[tx] = b2[tx]; w.gb3[tx] = gb3[tx]; }
  for (int i = tx; i < T && i < 512; i += 256) sg[i] = s_grid[i];
  __syncthreads();

  const int gid = blockIdx.x * 256 + tx;
  if (gid >= B) return;

  float4 y0v = ((const float4*)y0)[gid];
  float y[4] = {y0v.x, y0v.y, y0v.z, y0v.w};
  ((float4*)out)[gid] = y0v;  // t = 0 row

  for (int t = 0; t < T - 1; ++t) {
    const float h = sg[t + 1] - sg[t];
    float k[4], ksum[4], yt[4];

    fode(&w, y, k);
    #pragma unroll
    for (int c = 0; c < 4; ++c) { ksum[c] = k[c]; yt[c] = fmaf(0.5f * h, k[c], y[c]); }
    fode(&w, yt, k);
    #pragma unroll
    for (int c = 0; c < 4; ++c) { ksum[c] = fmaf(2.0f, k[c], ksum[c]); yt[c] = fmaf(0.5f * h, k[c], y[c]); }
    fode(&w, yt, k);
    #pragma unroll
    for (int c = 0; c < 4; ++c) { ksum[c] = fmaf(2.0f, k[c], ksum[c]); yt[c] = fmaf(h, k[c], y[c]); }
    fode(&w, yt, k);
    #pragma unroll
    for (int c = 0; c < 4; ++c)
      y[c] = fmaf(h * (1.0f / 6.0f), ksum[c] + k[c], y[c]);

    float4 yo; yo.x = y[0]; yo.y = y[1]; yo.z = y[2]; yo.w = y[3];
    ((float4*)out)[(size_t)(t + 1) * B + gid] = yo;
  }
}

extern "C" void kernel_launch(void* const* d_in, const int* in_sizes, int n_in,
                              void* d_out, int out_size, void* d_ws, size_t ws_size,
                              hipStream_t stream) {
  const float* s_grid = (const float*)d_in[0];
  const float* y0     = (const float*)d_in[1];
  const float* W1     = (const float*)d_in[2];
  const float* b1     = (const float*)d_in[3];
  const float* W2     = (const float*)d_in[4];
  const float* b2     = (const float*)d_in[5];
  const float* G1     = (const float*)d_in[6];
  const float* gb1    = (const float*)d_in[7];
  const float* l1g    = (const float*)d_in[8];
  const float* l1b    = (const float*)d_in[9];
  const float* G2     = (const float*)d_in[10];
  const float* gb2    = (const float*)d_in[11];
  const float* l2g    = (const float*)d_in[12];
  const float* l2b    = (const float*)d_in[13];
  const float* G3     = (const float*)d_in[14];
  const float* gb3    = (const float*)d_in[15];

  const int T = in_sizes[0];
  const int B = in_sizes[1] / 4;

  dim3 block(256);
  dim3 grid((B + 255) / 256);
  hipLaunchKernelGGL(ode_kernel, grid, block, 0, stream,
                     s_grid, y0, W1, b1, W2, b2, G1, gb1, l1g, l1b,
                     G2, gb2, l2g, l2b, G3, gb3, (float*)d_out, T, B);
}

// Round 3
// 136906.396 us; speedup vs baseline: 1.0030x; 1.0005x over previous
//
#include <hip/hip_runtime.h>
#include <math.h>

#define EPSV 1e-5f

struct __align__(16) WS {
  float W1[128]; float b1[32]; float W2[128]; float b2[4];
  float G1[128]; float gb1[32]; float l1g[32]; float l1b[32];
  float G2[1024]; float gb2[32]; float l2g[32]; float l2b[32];
  float G3[128]; float gb3[4];
};

__device__ __forceinline__ float ftanh(float x) {
  // tanh(x) = 1 - 2/(exp(2x)+1); clamp to avoid inf
  x = fminf(15.0f, fmaxf(-15.0f, x));
  float e = __expf(x + x);
  float r = __builtin_amdgcn_rcpf(e + 1.0f);
  return fmaf(-2.0f, r, 1.0f);
}

__device__ __forceinline__ float4 f4ma(float s, float4 w, float4 a) {
  a.x = fmaf(s, w.x, a.x); a.y = fmaf(s, w.y, a.y);
  a.z = fmaf(s, w.z, a.z); a.w = fmaf(s, w.w, a.w);
  return a;
}

__device__ __forceinline__ void lnorm32(float* t, const float* g, const float* b) {
  float s = 0.f, ss = 0.f;
  #pragma unroll
  for (int i = 0; i < 32; ++i) { s += t[i]; ss = fmaf(t[i], t[i], ss); }
  float m = s * 0.03125f;
  float v = fmaf(-m, m, ss * 0.03125f);
  float r = __frsqrt_rn(v + EPSV);
  #pragma unroll
  for (int i = 0; i < 32; ++i) t[i] = fmaf((t[i] - m) * r, g[i], b[i]);
}

// Register-lean f: peak live state is one 32-float array + accumulators.
__device__ __forceinline__ void fode(const WS* w, const float y[4], float out[4]) {
  const float4* W1v  = (const float4*)w->W1;
  const float4* b1v  = (const float4*)w->b1;
  const float4* W2v  = (const float4*)w->W2;
  const float4* G1v  = (const float4*)w->G1;
  const float4* gb1v = (const float4*)w->gb1;
  const float4* G2v  = (const float4*)w->G2;
  const float4* gb2v = (const float4*)w->gb2;
  const float4* G3v  = (const float4*)w->G3;

  // magnitude net, fused: no hidden array kept live
  float4 mag = *(const float4*)w->b2;
  #pragma unroll
  for (int j = 0; j < 8; ++j) {
    float4 a = b1v[j];
    #pragma unroll
    for (int i = 0; i < 4; ++i) a = f4ma(y[i], W1v[i * 8 + j], a);
    mag = f4ma(ftanh(a.x), W2v[4 * j + 0], mag);
    mag = f4ma(ftanh(a.y), W2v[4 * j + 1], mag);
    mag = f4ma(ftanh(a.z), W2v[4 * j + 2], mag);
    mag = f4ma(ftanh(a.w), W2v[4 * j + 3], mag);
  }

  // gating layer 1: t = LN(tanh(y@G1 + gb1))
  float t[32];
  #pragma unroll
  for (int j = 0; j < 8; ++j) {
    float4 a = gb1v[j];
    #pragma unroll
    for (int i = 0; i < 4; ++i) a = f4ma(y[i], G1v[i * 8 + j], a);
    t[4*j+0] = ftanh(a.x); t[4*j+1] = ftanh(a.y);
    t[4*j+2] = ftanh(a.z); t[4*j+3] = ftanh(a.w);
  }
  lnorm32(t, w->l1g, w->l1b);

  // gating layer 2: u = LN(tanh(t@G2 + gb2)); t dies as u completes
  float u[32];
  #pragma unroll
  for (int j = 0; j < 8; ++j) {
    float4 a = gb2v[j];
    #pragma unroll
    for (int i = 0; i < 32; ++i) a = f4ma(t[i], G2v[i * 8 + j], a);
    u[4*j+0] = ftanh(a.x); u[4*j+1] = ftanh(a.y);
    u[4*j+2] = ftanh(a.z); u[4*j+3] = ftanh(a.w);
  }
  lnorm32(u, w->l2g, w->l2b);

  // z = u@G3 + gb3 ; out = mag * exp(-z^2)
  float4 z = *(const float4*)w->gb3;
  #pragma unroll
  for (int i = 0; i < 32; ++i) z = f4ma(u[i], G3v[i], z);
  out[0] = mag.x * __expf(-z.x * z.x);
  out[1] = mag.y * __expf(-z.y * z.y);
  out[2] = mag.z * __expf(-z.z * z.z);
  out[3] = mag.w * __expf(-z.w * z.w);
}

// Occupancy is structurally 1 wave/SIMD (65536 threads / 256 CUs / 4 SIMDs):
// request min 1 wave/EU so the compiler may use the full 512-VGPR file and
// stop spilling to scratch (R1/R2: VGPR=256 cap + 248 GB spill traffic).
__global__ __launch_bounds__(256, 1) void ode_kernel(
    const float* __restrict__ s_grid, const float* __restrict__ y0,
    const float* __restrict__ W1, const float* __restrict__ b1,
    const float* __restrict__ W2, const float* __restrict__ b2,
    const float* __restrict__ G1, const float* __restrict__ gb1,
    const float* __restrict__ l1g, const float* __restrict__ l1b,
    const float* __restrict__ G2, const float* __restrict__ gb2,
    const float* __restrict__ l2g, const float* __restrict__ l2b,
    const float* __restrict__ G3, const float* __restrict__ gb3,
    float* __restrict__ out, int T, int B) {
  __shared__ WS w;
  __shared__ float sg[512];
  const int tx = threadIdx.x;

  for (int i = tx; i < 128; i += 256) {
    w.W1[i] = W1[i]; w.W2[i] = W2[i]; w.G1[i] = G1[i]; w.G3[i] = G3[i];
  }
  for (int i = tx; i < 1024; i += 256) w.G2[i] = G2[i];
  if (tx < 32) {
    w.b1[tx] = b1[tx]; w.gb1[tx] = gb1[tx];
    w.l1g[tx] = l1g[tx]; w.l1b[tx] = l1b[tx];
    w.gb2[tx] = gb2[tx];
    w.l2g[tx] = l2g[tx]; w.l2b[tx] = l2b[tx];
  }
  if (tx < 4) { w.b2[tx] = b2[tx]; w.gb3[tx] = gb3[tx]; }
  for (int i = tx; i < T && i < 512; i += 256) sg[i] = s_grid[i];
  __syncthreads();

  const int gid = blockIdx.x * 256 + tx;
  if (gid >= B) return;

  float4 y0v = ((const float4*)y0)[gid];
  float y[4] = {y0v.x, y0v.y, y0v.z, y0v.w};
  ((float4*)out)[gid] = y0v;  // t = 0 row

  for (int t = 0; t < T - 1; ++t) {
    const float h = sg[t + 1] - sg[t];
    float k[4], ksum[4], yt[4];

    fode(&w, y, k);
    #pragma unroll
    for (int c = 0; c < 4; ++c) { ksum[c] = k[c]; yt[c] = fmaf(0.5f * h, k[c], y[c]); }
    fode(&w, yt, k);
    #pragma unroll
    for (int c = 0; c < 4; ++c) { ksum[c] = fmaf(2.0f, k[c], ksum[c]); yt[c] = fmaf(0.5f * h, k[c], y[c]); }
    fode(&w, yt, k);
    #pragma unroll
    for (int c = 0; c < 4; ++c) { ksum[c] = fmaf(2.0f, k[c], ksum[c]); yt[c] = fmaf(h, k[c], y[c]); }
    fode(&w, yt, k);
    #pragma unroll
    for (int c = 0; c < 4; ++c)
      y[c] = fmaf(h * (1.0f / 6.0f), ksum[c] + k[c], y[c]);

    float4 yo; yo.x = y[0]; yo.y = y[1]; yo.z = y[2]; yo.w = y[3];
    ((float4*)out)[(size_t)(t + 1) * B + gid] = yo;
  }
}

extern "C" void kernel_launch(void* const* d_in, const int* in_sizes, int n_in,
                              void* d_out, int out_size, void* d_ws, size_t ws_size,
                              hipStream_t stream) {
  const float* s_grid = (const float*)d_in[0];
  const float* y0     = (const float*)d_in[1];
  const float* W1     = (const float*)d_in[2];
  const float* b1     = (const float*)d_in[3];
  const float* W2     = (const float*)d_in[4];
  const float* b2     = (const float*)d_in[5];
  const float* G1     = (const float*)d_in[6];
  const float* gb1    = (const float*)d_in[7];
  const float* l1g    = (const float*)d_in[8];
  const float* l1b    = (const float*)d_in[9];
  const float* G2     = (const float*)d_in[10];
  const float* gb2    = (const float*)d_in[11];
  const float* l2g    = (const float*)d_in[12];
  const float* l2b    = (const float*)d_in[13];
  const float* G3     = (const float*)d_in[14];
  const float* gb3    = (const float*)d_in[15];

  const int T = in_sizes[0];
  const int B = in_sizes[1] / 4;

  dim3 block(256);
  dim3 grid((B + 255) / 256);
  hipLaunchKernelGGL(ode_kernel, grid, block, 0, stream,
                     s_grid, y0, W1, b1, W2, b2, G1, gb1, l1g, l1b,
                     G2, gb2, l2g, l2b, G3, gb3, (float*)d_out, T, B);
}

// Round 4
// 9253.831 us; speedup vs baseline: 14.8383x; 14.7946x over previous
//
#include <hip/hip_runtime.h>
#include <math.h>

#define EPSV 1e-5f
#define SBAR() __builtin_amdgcn_sched_barrier(0)

struct __align__(16) WS {
  float W1[128]; float b1[32]; float W2[128]; float b2[4];
  float G1[128]; float gb1[32]; float l1g[32]; float l1b[32];
  float G2[1024]; float gb2[32]; float l2g[32]; float l2b[32];
  float G3[128]; float gb3[4];
};

__device__ __forceinline__ float ftanh(float x) {
  // tanh(x) = 1 - 2/(exp(2x)+1); clamp to avoid inf
  x = fminf(15.0f, fmaxf(-15.0f, x));
  float e = __expf(x + x);
  float r = __builtin_amdgcn_rcpf(e + 1.0f);
  return fmaf(-2.0f, r, 1.0f);
}

__device__ __forceinline__ float4 f4ma(float s, float4 w, float4 a) {
  a.x = fmaf(s, w.x, a.x); a.y = fmaf(s, w.y, a.y);
  a.z = fmaf(s, w.z, a.z); a.w = fmaf(s, w.w, a.w);
  return a;
}

__device__ __forceinline__ void lnorm32(float* t, const float* g, const float* b) {
  float s = 0.f, ss = 0.f;
  #pragma unroll
  for (int i = 0; i < 32; ++i) { s += t[i]; ss = fmaf(t[i], t[i], ss); }
  float m = s * 0.03125f;
  float v = fmaf(-m, m, ss * 0.03125f);
  float r = __frsqrt_rn(v + EPSV);
  #pragma unroll
  for (int i = 0; i < 32; ++i) t[i] = fmaf((t[i] - m) * r, g[i], b[i]);
}

// sched_barrier(0) after each weight-column phase caps the scheduler's
// load-hoisting window (~<=16 float4 in flight) so VGPR demand stays
// under the 256 arch-VGPR cap -> no scratch spill. All indices static.
__device__ __forceinline__ void fode(const WS* w, const float y[4], float out[4]) {
  const float4* W1v  = (const float4*)w->W1;
  const float4* b1v  = (const float4*)w->b1;
  const float4* W2v  = (const float4*)w->W2;
  const float4* G1v  = (const float4*)w->G1;
  const float4* gb1v = (const float4*)w->gb1;
  const float4* G2v  = (const float4*)w->G2;
  const float4* gb2v = (const float4*)w->gb2;
  const float4* G3v  = (const float4*)w->G3;

  // magnitude net, fused: no hidden array kept live
  float4 mag = *(const float4*)w->b2;
  #pragma unroll
  for (int j = 0; j < 8; ++j) {
    float4 a = b1v[j];
    #pragma unroll
    for (int i = 0; i < 4; ++i) a = f4ma(y[i], W1v[i * 8 + j], a);
    mag = f4ma(ftanh(a.x), W2v[4 * j + 0], mag);
    mag = f4ma(ftanh(a.y), W2v[4 * j + 1], mag);
    mag = f4ma(ftanh(a.z), W2v[4 * j + 2], mag);
    mag = f4ma(ftanh(a.w), W2v[4 * j + 3], mag);
    SBAR();
  }

  // gating layer 1: t = LN(tanh(y@G1 + gb1))
  float t[32];
  #pragma unroll
  for (int j = 0; j < 8; ++j) {
    float4 a = gb1v[j];
    #pragma unroll
    for (int i = 0; i < 4; ++i) a = f4ma(y[i], G1v[i * 8 + j], a);
    t[4*j+0] = ftanh(a.x); t[4*j+1] = ftanh(a.y);
    t[4*j+2] = ftanh(a.z); t[4*j+3] = ftanh(a.w);
    SBAR();
  }
  lnorm32(t, w->l1g, w->l1b);
  SBAR();

  // gating layer 2: u = LN(tanh(t@G2 + gb2)); fence mid-column too
  // (32 float4 loads per column would otherwise be hoisted together)
  float u[32];
  #pragma unroll
  for (int j = 0; j < 8; ++j) {
    float4 a = gb2v[j];
    #pragma unroll
    for (int i = 0; i < 32; ++i) {
      a = f4ma(t[i], G2v[i * 8 + j], a);
      if (i == 15) SBAR();
    }
    u[4*j+0] = ftanh(a.x); u[4*j+1] = ftanh(a.y);
    u[4*j+2] = ftanh(a.z); u[4*j+3] = ftanh(a.w);
    SBAR();
  }
  lnorm32(u, w->l2g, w->l2b);
  SBAR();

  // z = u@G3 + gb3 ; out = mag * exp(-z^2)
  float4 z = *(const float4*)w->gb3;
  #pragma unroll
  for (int i = 0; i < 32; ++i) {
    z = f4ma(u[i], G3v[i], z);
    if ((i & 7) == 7) SBAR();
  }
  out[0] = mag.x * __expf(-z.x * z.x);
  out[1] = mag.y * __expf(-z.y * z.y);
  out[2] = mag.z * __expf(-z.z * z.z);
  out[3] = mag.w * __expf(-z.w * z.w);
}

__global__ __launch_bounds__(256, 1) void ode_kernel(
    const float* __restrict__ s_grid, const float* __restrict__ y0,
    const float* __restrict__ W1, const float* __restrict__ b1,
    const float* __restrict__ W2, const float* __restrict__ b2,
    const float* __restrict__ G1, const float* __restrict__ gb1,
    const float* __restrict__ l1g, const float* __restrict__ l1b,
    const float* __restrict__ G2, const float* __restrict__ gb2,
    const float* __restrict__ l2g, const float* __restrict__ l2b,
    const float* __restrict__ G3, const float* __restrict__ gb3,
    float* __restrict__ out, int T, int B) {
  __shared__ WS w;
  __shared__ float sg[512];
  const int tx = threadIdx.x;

  for (int i = tx; i < 128; i += 256) {
    w.W1[i] = W1[i]; w.W2[i] = W2[i]; w.G1[i] = G1[i]; w.G3[i] = G3[i];
  }
  for (int i = tx; i < 1024; i += 256) w.G2[i] = G2[i];
  if (tx < 32) {
    w.b1[tx] = b1[tx]; w.gb1[tx] = gb1[tx];
    w.l1g[tx] = l1g[tx]; w.l1b[tx] = l1b[tx];
    w.gb2[tx] = gb2[tx];
    w.l2g[tx] = l2g[tx]; w.l2b[tx] = l2b[tx];
  }
  if (tx < 4) { w.b2[tx] = b2[tx]; w.gb3[tx] = gb3[tx]; }
  for (int i = tx; i < T && i < 512; i += 256) sg[i] = s_grid[i];
  __syncthreads();

  const int gid = blockIdx.x * 256 + tx;
  if (gid >= B) return;

  float4 y0v = ((const float4*)y0)[gid];
  float y[4] = {y0v.x, y0v.y, y0v.z, y0v.w};
  ((float4*)out)[gid] = y0v;  // t = 0 row

  #pragma unroll 1
  for (int t = 0; t < T - 1; ++t) {
    const float h = sg[t + 1] - sg[t];
    float k[4], ksum[4], yt[4];

    fode(&w, y, k);
    #pragma unroll
    for (int c = 0; c < 4; ++c) { ksum[c] = k[c]; yt[c] = fmaf(0.5f * h, k[c], y[c]); }
    SBAR();
    fode(&w, yt, k);
    #pragma unroll
    for (int c = 0; c < 4; ++c) { ksum[c] = fmaf(2.0f, k[c], ksum[c]); yt[c] = fmaf(0.5f * h, k[c], y[c]); }
    SBAR();
    fode(&w, yt, k);
    #pragma unroll
    for (int c = 0; c < 4; ++c) { ksum[c] = fmaf(2.0f, k[c], ksum[c]); yt[c] = fmaf(h, k[c], y[c]); }
    SBAR();
    fode(&w, yt, k);
    #pragma unroll
    for (int c = 0; c < 4; ++c)
      y[c] = fmaf(h * (1.0f / 6.0f), ksum[c] + k[c], y[c]);

    float4 yo; yo.x = y[0]; yo.y = y[1]; yo.z = y[2]; yo.w = y[3];
    ((float4*)out)[(size_t)(t + 1) * B + gid] = yo;
  }
}

extern "C" void kernel_launch(void* const* d_in, const int* in_sizes, int n_in,
                              void* d_out, int out_size, void* d_ws, size_t ws_size,
                              hipStream_t stream) {
  const float* s_grid = (const float*)d_in[0];
  const float* y0     = (const float*)d_in[1];
  const float* W1     = (const float*)d_in[2];
  const float* b1     = (const float*)d_in[3];
  const float* W2     = (const float*)d_in[4];
  const float* b2     = (const float*)d_in[5];
  const float* G1     = (const float*)d_in[6];
  const float* gb1    = (const float*)d_in[7];
  const float* l1g    = (const float*)d_in[8];
  const float* l1b    = (const float*)d_in[9];
  const float* G2     = (const float*)d_in[10];
  const float* gb2    = (const float*)d_in[11];
  const float* l2g    = (const float*)d_in[12];
  const float* l2b    = (const float*)d_in[13];
  const float* G3     = (const float*)d_in[14];
  const float* gb3    = (const float*)d_in[15];

  const int T = in_sizes[0];
  const int B = in_sizes[1] / 4;

  dim3 block(256);
  dim3 grid((B + 255) / 256);
  hipLaunchKernelGGL(ode_kernel, grid, block, 0, stream,
                     s_grid, y0, W1, b1, W2, b2, G1, gb1, l1g, l1b,
                     G2, gb2, l2g, l2b, G3, gb3, (float*)d_out, T, B);
}

// Round 5
// 6252.622 us; speedup vs baseline: 21.9606x; 1.4800x over previous
//
#include <hip/hip_runtime.h>
#include <math.h>

#define EPSV 1e-5f
#define SBAR() __builtin_amdgcn_sched_barrier(0)

struct __align__(16) WS {
  float W1[128]; float b1[32]; float W2[128]; float b2[4];
  float G1[128]; float gb1[32]; float l1g[32]; float l1b[32];
  float G2[1024]; float gb2[32]; float l2g[32]; float l2b[32];
  float G3[128]; float gb3[4];
};

__device__ __forceinline__ float ftanh(float x) {
  // tanh(x) = 1 - 2/(exp(2x)+1); clamp to avoid inf
  x = fminf(15.0f, fmaxf(-15.0f, x));
  float e = __expf(x + x);
  float r = __builtin_amdgcn_rcpf(e + 1.0f);
  return fmaf(-2.0f, r, 1.0f);
}

__device__ __forceinline__ float4 f4ma(float s, float4 w, float4 a) {
  a.x = fmaf(s, w.x, a.x); a.y = fmaf(s, w.y, a.y);
  a.z = fmaf(s, w.z, a.z); a.w = fmaf(s, w.w, a.w);
  return a;
}

// LayerNorm over 32 values held 16-per-lane across a lane pair.
// g/b pointers pre-offset to this lane's 16 rows.
__device__ __forceinline__ void lnorm16_pair(float* t, const float* g, const float* b) {
  float s = 0.f, ss = 0.f;
  #pragma unroll
  for (int i = 0; i < 16; ++i) { s += t[i]; ss = fmaf(t[i], t[i], ss); }
  s  += __shfl_xor(s, 1);
  ss += __shfl_xor(ss, 1);
  float m = s * 0.03125f;
  float v = fmaf(-m, m, ss * 0.03125f);
  float r = __frsqrt_rn(v + EPSV);
  #pragma unroll
  for (int i = 0; i < 16; ++i) t[i] = fmaf((t[i] - m) * r, g[i], b[i]);
}

// f-eval split across a lane pair: lane p in {0,1} owns output columns
// [16p, 16p+16) of every 32-wide hidden layer. ~half the FMAs and tanh
// per lane vs the 1-lane version; pair exchanges via __shfl_xor(.,1).
__device__ __forceinline__ void fode(const WS* w, int p, bool pb,
                                     const float y[4], float out[4]) {
  const float4* W1v  = (const float4*)w->W1;
  const float4* b1v  = (const float4*)w->b1;
  const float4* W2v  = (const float4*)w->W2;
  const float4* G1v  = (const float4*)w->G1;
  const float4* gb1v = (const float4*)w->gb1;
  const float4* G2v  = (const float4*)w->G2;
  const float4* gb2v = (const float4*)w->gb2;
  const float4* G3v  = (const float4*)w->G3;
  const int j0 = p * 4;    // my float4 column-group base (of 8)
  const int r0 = p * 16;   // my row base (of 32)

  // ---- magnitude net: partial over my 16 hidden units ----
  float4 magp = make_float4(0.f, 0.f, 0.f, 0.f);
  #pragma unroll
  for (int j = 0; j < 4; ++j) {
    float4 a = b1v[j0 + j];
    #pragma unroll
    for (int i = 0; i < 4; ++i) a = f4ma(y[i], W1v[i * 8 + j0 + j], a);
    magp = f4ma(ftanh(a.x), W2v[r0 + 4 * j + 0], magp);
    magp = f4ma(ftanh(a.y), W2v[r0 + 4 * j + 1], magp);
    magp = f4ma(ftanh(a.z), W2v[r0 + 4 * j + 2], magp);
    magp = f4ma(ftanh(a.w), W2v[r0 + 4 * j + 3], magp);
    SBAR();
  }

  // ---- gating layer 1: my 16 of t = LN(tanh(y@G1+gb1)) ----
  float tm[16];
  #pragma unroll
  for (int j = 0; j < 4; ++j) {
    float4 a = gb1v[j0 + j];
    #pragma unroll
    for (int i = 0; i < 4; ++i) a = f4ma(y[i], G1v[i * 8 + j0 + j], a);
    tm[4*j+0] = ftanh(a.x); tm[4*j+1] = ftanh(a.y);
    tm[4*j+2] = ftanh(a.z); tm[4*j+3] = ftanh(a.w);
    SBAR();
  }
  lnorm16_pair(tm, w->l1g + r0, w->l1b + r0);

  // ---- exchange: build full 32-vector (static indexing only) ----
  float tf[32];
  #pragma unroll
  for (int i = 0; i < 16; ++i) {
    float o = __shfl_xor(tm[i], 1);
    tf[i]      = pb ? o     : tm[i];
    tf[16 + i] = pb ? tm[i] : o;
  }
  SBAR();

  // ---- gating layer 2: my 16 of u = LN(tanh(t@G2+gb2)) ----
  float um[16];
  #pragma unroll
  for (int j = 0; j < 4; ++j) {
    float4 a = gb2v[j0 + j];
    #pragma unroll
    for (int i = 0; i < 32; ++i) {
      a = f4ma(tf[i], G2v[i * 8 + j0 + j], a);
      if (i == 15) SBAR();
    }
    um[4*j+0] = ftanh(a.x); um[4*j+1] = ftanh(a.y);
    um[4*j+2] = ftanh(a.z); um[4*j+3] = ftanh(a.w);
    SBAR();
  }
  lnorm16_pair(um, w->l2g + r0, w->l2b + r0);

  // ---- G3 partial over my 16 rows, then pair-reduce ----
  float4 zp = make_float4(0.f, 0.f, 0.f, 0.f);
  #pragma unroll
  for (int i = 0; i < 16; ++i) {
    zp = f4ma(um[i], G3v[r0 + i], zp);
    if (i == 7) SBAR();
  }
  SBAR();

  float4 b2v  = *(const float4*)w->b2;
  float4 gb3v = *(const float4*)w->gb3;
  float zx = zp.x + __shfl_xor(zp.x, 1) + gb3v.x;
  float zy = zp.y + __shfl_xor(zp.y, 1) + gb3v.y;
  float zz = zp.z + __shfl_xor(zp.z, 1) + gb3v.z;
  float zw = zp.w + __shfl_xor(zp.w, 1) + gb3v.w;
  float mx = magp.x + __shfl_xor(magp.x, 1) + b2v.x;
  float my = magp.y + __shfl_xor(magp.y, 1) + b2v.y;
  float mz = magp.z + __shfl_xor(magp.z, 1) + b2v.z;
  float mw = magp.w + __shfl_xor(magp.w, 1) + b2v.w;
  out[0] = mx * __expf(-zx * zx);
  out[1] = my * __expf(-zy * zy);
  out[2] = mz * __expf(-zz * zz);
  out[3] = mw * __expf(-zw * zw);
}

__global__ __launch_bounds__(256, 2) void ode_kernel(
    const float* __restrict__ s_grid, const float* __restrict__ y0,
    const float* __restrict__ W1, const float* __restrict__ b1,
    const float* __restrict__ W2, const float* __restrict__ b2,
    const float* __restrict__ G1, const float* __restrict__ gb1,
    const float* __restrict__ l1g, const float* __restrict__ l1b,
    const float* __restrict__ G2, const float* __restrict__ gb2,
    const float* __restrict__ l2g, const float* __restrict__ l2b,
    const float* __restrict__ G3, const float* __restrict__ gb3,
    float* __restrict__ out, int T, int B) {
  __shared__ WS w;
  __shared__ float sg[512];
  const int tx = threadIdx.x;

  for (int i = tx; i < 128; i += 256) {
    w.W1[i] = W1[i]; w.W2[i] = W2[i]; w.G1[i] = G1[i]; w.G3[i] = G3[i];
  }
  for (int i = tx; i < 1024; i += 256) w.G2[i] = G2[i];
  if (tx < 32) {
    w.b1[tx] = b1[tx]; w.gb1[tx] = gb1[tx];
    w.l1g[tx] = l1g[tx]; w.l1b[tx] = l1b[tx];
    w.gb2[tx] = gb2[tx];
    w.l2g[tx] = l2g[tx]; w.l2b[tx] = l2b[tx];
  }
  if (tx < 4) { w.b2[tx] = b2[tx]; w.gb3[tx] = gb3[tx]; }
  for (int i = tx; i < T && i < 512; i += 256) sg[i] = s_grid[i];
  __syncthreads();

  const int tid = blockIdx.x * 256 + tx;
  const int sys = tid >> 1;        // system index (2 lanes per system)
  const int p   = tid & 1;         // which half of the hidden layers
  const bool pb = (p != 0);
  if (sys >= B) return;

  float4 y0v = ((const float4*)y0)[sys];
  float y[4] = {y0v.x, y0v.y, y0v.z, y0v.w};
  if (!pb) ((float4*)out)[sys] = y0v;  // t = 0 row

  #pragma unroll 1
  for (int t = 0; t < T - 1; ++t) {
    const float h = sg[t + 1] - sg[t];
    float k[4], ksum[4], yt[4];

    fode(&w, p, pb, y, k);
    #pragma unroll
    for (int c = 0; c < 4; ++c) { ksum[c] = k[c]; yt[c] = fmaf(0.5f * h, k[c], y[c]); }
    SBAR();
    fode(&w, p, pb, yt, k);
    #pragma unroll
    for (int c = 0; c < 4; ++c) { ksum[c] = fmaf(2.0f, k[c], ksum[c]); yt[c] = fmaf(0.5f * h, k[c], y[c]); }
    SBAR();
    fode(&w, p, pb, yt, k);
    #pragma unroll
    for (int c = 0; c < 4; ++c) { ksum[c] = fmaf(2.0f, k[c], ksum[c]); yt[c] = fmaf(h, k[c], y[c]); }
    SBAR();
    fode(&w, p, pb, yt, k);
    #pragma unroll
    for (int c = 0; c < 4; ++c)
      y[c] = fmaf(h * (1.0f / 6.0f), ksum[c] + k[c], y[c]);

    if (!pb) {
      float4 yo; yo.x = y[0]; yo.y = y[1]; yo.z = y[2]; yo.w = y[3];
      ((float4*)out)[(size_t)(t + 1) * B + sys] = yo;
    }
  }
}

extern "C" void kernel_launch(void* const* d_in, const int* in_sizes, int n_in,
                              void* d_out, int out_size, void* d_ws, size_t ws_size,
                              hipStream_t stream) {
  const float* s_grid = (const float*)d_in[0];
  const float* y0     = (const float*)d_in[1];
  const float* W1     = (const float*)d_in[2];
  const float* b1     = (const float*)d_in[3];
  const float* W2     = (const float*)d_in[4];
  const float* b2     = (const float*)d_in[5];
  const float* G1     = (const float*)d_in[6];
  const float* gb1    = (const float*)d_in[7];
  const float* l1g    = (const float*)d_in[8];
  const float* l1b    = (const float*)d_in[9];
  const float* G2     = (const float*)d_in[10];
  const float* gb2    = (const float*)d_in[11];
  const float* l2g    = (const float*)d_in[12];
  const float* l2b    = (const float*)d_in[13];
  const float* G3     = (const float*)d_in[14];
  const float* gb3    = (const float*)d_in[15];

  const int T = in_sizes[0];
  const int B = in_sizes[1] / 4;

  const int threads = 2 * B;  // two lanes per system
  dim3 block(256);
  dim3 grid((threads + 255) / 256);
  hipLaunchKernelGGL(ode_kernel, grid, block, 0, stream,
                     s_grid, y0, W1, b1, W2, b2, G1, gb1, l1g, l1b,
                     G2, gb2, l2g, l2b, G3, gb3, (float*)d_out, T, B);
}